// Round 14
// baseline (186.607 us; speedup 1.0000x reference)
//
#include <hip/hip_runtime.h>
#include <hip/hip_bf16.h>

#define N_NODES 10000
#define N_EDGES 320000
#define N_GRAPHS 64
#define DIM 256
#define ADIM 118
#define OUTD 100
#define HALF_CAP 72      // per-sub-counter slots (mean 16, max-degree-66 worst case fits)
#define CAP 144          // 2 * HALF_CAP per node
#define CURPAD 16        // ints per counter slot -> one 64B line per counter

typedef short bf8_t __attribute__((ext_vector_type(8)));
typedef float f4_t  __attribute__((ext_vector_type(4)));
typedef float f2_t  __attribute__((ext_vector_type(2)));

__device__ __forceinline__ unsigned short f2bf(float f) {
    unsigned u = __float_as_uint(f);
    u += 0x7FFFu + ((u >> 16) & 1u);   // round-to-nearest-even
    return (unsigned short)(u >> 16);
}
__device__ __forceinline__ float bf2f(unsigned short s) {
    return __uint_as_float(((unsigned)s) << 16);
}
__device__ __forceinline__ f2_t pk_fma(f2_t a, f2_t b, f2_t c) {
    f2_t d;
    asm("v_pk_fma_f32 %0, %1, %2, %3" : "=v"(d) : "v"(a), "v"(b), "v"(c));
    return d;
}
__device__ __forceinline__ f2_t pk_add(f2_t a, f2_t b) {
    f2_t d;
    asm("v_pk_add_f32 %0, %1, %2" : "=v"(d) : "v"(a), "v"(b));
    return d;
}

// ====== fused setup: CSR fill (0-1249) || Wg transpose (1250-1281) ||
// ====== node embedding (1282-2561, reads Wn directly)
// Fill uses 2 sub-counters per node (parity of edge index, separate cache
// lines) -> same-address atomic chain length 32 -> 16.
#define AST 136
__global__ __launch_bounds__(256) void setup_k(
    const int* __restrict__ src, const int* __restrict__ dst,
    const float* __restrict__ len, int* __restrict__ cnt, int2* __restrict__ epack,
    const float* __restrict__ Wn, const float* __restrict__ Wg,
    unsigned short* __restrict__ WgT,
    const float* __restrict__ an, const float* __restrict__ bn,
    const float* __restrict__ be, unsigned short* __restrict__ hbf) {
    const int B = blockIdx.x;
    const int t = threadIdx.x;
    if (B < 1250) {
        // ---------- CSR fill: 1250*256 = 320000 edges exactly ----------
        int j = B * 256 + t;
        int d = dst[j];
        int sub = j & 1;                      // parity split: 2 chains of ~16
        int pos = atomicAdd(&cnt[((d << 1) | sub) << 4], 1);
        if (pos < HALF_CAP)
            epack[d * CAP + sub * HALF_CAP + pos] =
                make_int2(src[j] * DIM, __float_as_int(len[j]));
        return;
    }
    if (B < 1282) {
        // ---------- Wg [2][256][256] f32 -> WgT bf16, LDS-tiled transpose ----------
        __shared__ unsigned short lds[64][65];    // +1 pad
        int r = B - 1250;
        int l = r >> 4; r &= 15;
        int kt = r & 3, ct = r >> 2;
        const float* srcp = Wg + l * 65536;
        unsigned short* dstp = WgT + l * 65536;
        #pragma unroll
        for (int i = 0; i < 16; ++i) {            // coalesced load 64x64 tile
            int idx = t + i * 256;
            int rr = idx >> 6, cc = idx & 63;
            lds[rr][cc] = f2bf(srcp[(size_t)(kt * 64 + rr) * 256 + ct * 64 + cc]);
        }
        __syncthreads();
        #pragma unroll
        for (int i = 0; i < 16; ++i) {            // coalesced transposed store
            int idx = t + i * 256;
            int r2 = idx >> 6, cc2 = idx & 63;
            dstp[(size_t)(ct * 64 + r2) * 256 + kt * 64 + cc2] = lds[cc2][r2];
        }
        return;
    }
    // ---------- node embedding: hbf = bf16(an @ W_node + b_node + b_edge) ----------
    const int e = B - 1282;                       // 0..1279
    const int half = e & 1;
    const int tile = e >> 1;                      // 0..639
    if (tile >= 625) return;
    __shared__ __attribute__((aligned(16))) unsigned short xs[16 * AST];
    const int base = tile * 16;
    for (int i = t; i < 16 * (AST - ADIM); i += 256) {
        int r = i / (AST - ADIM);
        int c = i - r * (AST - ADIM);
        xs[r * AST + ADIM + c] = 0;
    }
    for (int i = t; i < 16 * 59; i += 256) {      // 118 = 2*59, float2 loads
        int r = i / 59;
        int c = (i - r * 59) * 2;
        float2 v = *(const float2*)(an + (size_t)(base + r) * ADIM + c);
        xs[r * AST + c]     = f2bf(v.x);
        xs[r * AST + c + 1] = f2bf(v.y);
    }
    __syncthreads();
    const int wave = t >> 6, lane = t & 63;
    const int m = lane & 15, quad = lane >> 4;
    bf8_t afrag[4];
    #pragma unroll
    for (int s = 0; s < 4; ++s)
        afrag[s] = *(const bf8_t*)&xs[m * AST + s * 32 + quad * 8];
    const int colbase = half * 128 + wave * 32;
    #pragma unroll
    for (int ct = 0; ct < 2; ++ct) {
        const int col = colbase + ct * 16 + m;
        f4_t acc = (f4_t){0.f, 0.f, 0.f, 0.f};
        #pragma unroll
        for (int s = 0; s < 4; ++s) {
            bf8_t bfrag;
            #pragma unroll
            for (int j = 0; j < 8; ++j) {
                int k = s * 32 + quad * 8 + j;
                float v = (k < ADIM) ? Wn[(size_t)k * DIM + col] : 0.f;
                bfrag[j] = (short)f2bf(v);
            }
            acc = __builtin_amdgcn_mfma_f32_16x16x32_bf16(afrag[s], bfrag, acc, 0, 0, 0);
        }
        float bb = bn[col] + be[col];             // fold b_edge
        #pragma unroll
        for (int r = 0; r < 4; ++r)
            hbf[(size_t)(base + quad * 4 + r) * DIM + col] = f2bf(acc[r] + bb);
    }
}

// ---------- gather: XCD-pinned dim-halves, packed-f32 math, 2 sub-segments ----------
__global__ __launch_bounds__(256) void gather_k(
    const unsigned short* __restrict__ hbf, const int* __restrict__ cnt,
    const int2* __restrict__ epack, const float* __restrict__ We,
    const float* __restrict__ be, const float* __restrict__ epsp, int layer,
    unsigned short* __restrict__ xbf) {
    const int B = blockIdx.x;                 // grid = 5000
    const int half = (B >> 2) & 1;
    const int k = (B >> 3) * 4 + (B & 3);     // node tile [0, 2500)
    const int wave = threadIdx.x >> 6, lane = threadIdx.x & 63;
    const int node = __builtin_amdgcn_readfirstlane(k * 4 + wave);
    const int sub = lane >> 4;
    const int dp = half * 128 + (lane & 15) * 8;
    float4 wa = *(const float4*)(We + dp);
    float4 wc = *(const float4*)(We + dp + 4);
    f2_t ww[4];
    ww[0] = (f2_t){wa.x, wa.y}; ww[1] = (f2_t){wa.z, wa.w};
    ww[2] = (f2_t){wc.x, wc.y}; ww[3] = (f2_t){wc.z, wc.w};
    const float eps1 = 1.f + epsp[layer];
    float4 ba = *(const float4*)(be + dp);
    float4 bc = *(const float4*)(be + dp + 4);
    f2_t ebe[4];
    ebe[0] = (f2_t){eps1 * ba.x, eps1 * ba.y};
    ebe[1] = (f2_t){eps1 * ba.z, eps1 * ba.w};
    ebe[2] = (f2_t){eps1 * bc.x, eps1 * bc.y};
    ebe[3] = (f2_t){eps1 * bc.z, eps1 * bc.w};
    f2_t acc2[4];
    #pragma unroll
    for (int i = 0; i < 4; ++i) acc2[i] = (f2_t){0.f, 0.f};
    const unsigned short* hb = hbf + dp;
    const int ce0 = min(__builtin_amdgcn_readfirstlane(cnt[(node << 1) << 4]), HALF_CAP);
    const int ce1 = min(__builtin_amdgcn_readfirstlane(cnt[((node << 1) | 1) << 4]), HALF_CAP);
#define GATH(q) { \
    const uint4 ar = *(const uint4*)(hb + (unsigned)(q).x); \
    const float l = __int_as_float((q).y); \
    f2_t lpk; lpk.x = l; lpk.y = l; \
    _Pragma("unroll") \
    for (int p = 0; p < 4; ++p) { \
        unsigned u = (&ar.x)[p]; \
        f2_t h; \
        h.x = __uint_as_float(u << 16); \
        h.y = __uint_as_float(u & 0xffff0000u); \
        f2_t mm = pk_fma(lpk, ww[p], h); \
        mm.x = fmaxf(mm.x, 0.f); \
        mm.y = fmaxf(mm.y, 0.f); \
        acc2[p] = pk_add(acc2[p], mm); \
    } }
    #pragma unroll 1
    for (int sseg = 0; sseg < 2; ++sseg) {
        const int ce = sseg ? ce1 : ce0;
        const int2* ep = epack + node * CAP + sseg * HALF_CAP;
        int t = 0;
        for (; t + 7 < ce; t += 8) {
            int2 qa = ep[t + sub], qb = ep[t + 4 + sub];
            GATH(qa) GATH(qb)
        }
        for (; t + 3 < ce; t += 4) {
            int2 q = ep[t + sub];
            GATH(q)
        }
        if (t < ce && t + sub < ce) {
            int2 q = ep[t + sub];
            GATH(q)
        }
    }
#undef GATH
    #pragma unroll
    for (int p = 0; p < 4; ++p) {
        acc2[p].x += __shfl(acc2[p].x, lane ^ 16, 64);
        acc2[p].y += __shfl(acc2[p].y, lane ^ 16, 64);
        acc2[p].x += __shfl(acc2[p].x, lane ^ 32, 64);
        acc2[p].y += __shfl(acc2[p].y, lane ^ 32, 64);
    }
    if (sub == 0) {
        const uint4 hr = *(const uint4*)(hbf + (size_t)node * DIM + dp);
        bf8_t o;
        #pragma unroll
        for (int p = 0; p < 4; ++p) {
            unsigned u = (&hr.x)[p];
            float hlo = __uint_as_float(u << 16);
            float hhi = __uint_as_float(u & 0xffff0000u);
            o[2 * p]     = (short)f2bf(fmaf(eps1, hlo, acc2[p].x - ebe[p].x));
            o[2 * p + 1] = (short)f2bf(fmaf(eps1, hhi, acc2[p].y - ebe[p].y));
        }
        *(bf8_t*)(xbf + (size_t)node * DIM + dp) = o;
    }
}

// ---------- MFMA node update: block = 16 rows x 128 cols (one half) ----------
#define XST 264
__global__ __launch_bounds__(256) void update_k(
    const unsigned short* __restrict__ xbf,
    const unsigned short* __restrict__ WT, const float* __restrict__ b,
    const float* __restrict__ be, unsigned short* __restrict__ hout,
    const int* __restrict__ gid, float* __restrict__ feat, int do_pool) {
    const int B = blockIdx.x;                 // grid 1280, guard below
    const int half = (B >> 2) & 1;
    const int tile = (B >> 3) * 4 + (B & 3);
    if (tile >= 625) return;
    __shared__ __attribute__((aligned(16))) unsigned short xs[16 * XST];
    __shared__ int gids[16];
    const int base = tile * 16;
    const int tid = threadIdx.x;
    #pragma unroll
    for (int cch = tid; cch < 512; cch += 256) {     // 16 rows x full 256 dims
        int rr = cch >> 5, k0 = (cch & 31) * 8;
        *(bf8_t*)&xs[rr * XST + k0] = *(const bf8_t*)(xbf + (size_t)(base + rr) * DIM + k0);
    }
    if (do_pool && tid < 16) gids[tid] = gid[base + tid];
    __syncthreads();
    const int wave = tid >> 6, lane = tid & 63;
    const int m = lane & 15, quad = lane >> 4;
    bf8_t afrag[8];
    #pragma unroll
    for (int s = 0; s < 8; ++s)
        afrag[s] = *(const bf8_t*)&xs[m * XST + s * 32 + quad * 8];
    const int colbase = half * 128 + wave * 32;
    #pragma unroll
    for (int ct = 0; ct < 2; ++ct) {
        const int col = colbase + ct * 16 + m;
        f4_t acc2 = (f4_t){0.f, 0.f, 0.f, 0.f};
        const unsigned short* wp = WT + (size_t)col * DIM + quad * 8;
        #pragma unroll
        for (int s = 0; s < 8; ++s) {
            bf8_t bfrag = *(const bf8_t*)(wp + s * 32);
            acc2 = __builtin_amdgcn_mfma_f32_16x16x32_bf16(afrag[s], bfrag, acc2, 0, 0, 0);
        }
        if (!do_pool) {
            const float bb = b[col] + be[col];   // fold b_edge for next gather
            #pragma unroll
            for (int r = 0; r < 4; ++r)
                hout[(size_t)(base + quad * 4 + r) * DIM + col] = f2bf(acc2[r] + bb);
        } else {
            const float bb = b[col];
            if (gids[0] == gids[15]) {
                float v = acc2[0] + acc2[1] + acc2[2] + acc2[3] + 4.f * bb;
                v += __shfl(v, lane ^ 16, 64);
                v += __shfl(v, lane ^ 32, 64);
                if (quad == 0) atomicAdd(&feat[(size_t)gids[0] * DIM + col], v);
            } else {
                float run = 0.f;
                int cur = gids[quad * 4];
                #pragma unroll
                for (int r = 0; r < 4; ++r) {
                    int g = gids[quad * 4 + r];
                    if (g != cur) {
                        atomicAdd(&feat[(size_t)cur * DIM + col], run);
                        run = 0.f;
                        cur = g;
                    }
                    run += acc2[r] + bb;
                }
                atomicAdd(&feat[(size_t)cur * DIM + col], run);
            }
        }
    }
}

// ---------- parallel head: 256 blocks (4/graph, 25 outputs each) ----------
__global__ __launch_bounds__(256) void headmm_k(
    const float* __restrict__ feat, const float* __restrict__ Wm,
    const float* __restrict__ bm, const float* __restrict__ epsp,
    float* __restrict__ out) {
    __shared__ float frow[DIM];
    __shared__ float smn[4], smx[4], sMn, sMx;
    __shared__ float spart[8][32];
    const int g  = blockIdx.x >> 2;           // graph
    const int o0 = (blockIdx.x & 3) * 25;     // output base (o0+24 <= 99)
    const int tid = threadIdx.x;
    const int wave = tid >> 6, lane = tid & 63;
    float mn = 3.4e38f, mx = -3.4e38f;
    const float4* f4 = (const float4*)feat;
    for (int i = tid; i < N_GRAPHS * DIM / 4; i += 256) {   // 16 iterations
        float4 v = f4[i];
        mn = fminf(mn, fminf(fminf(v.x, v.y), fminf(v.z, v.w)));
        mx = fmaxf(mx, fmaxf(fmaxf(v.x, v.y), fmaxf(v.z, v.w)));
    }
    frow[tid] = feat[g * DIM + tid];
    #pragma unroll
    for (int off = 32; off > 0; off >>= 1) {
        mn = fminf(mn, __shfl_down(mn, off, 64));
        mx = fmaxf(mx, __shfl_down(mx, off, 64));
    }
    if (lane == 0) { smn[wave] = mn; smx[wave] = mx; }
    __syncthreads();
    if (tid == 0) {
        sMn = fminf(fminf(smn[0], smn[1]), fminf(smn[2], smn[3]));
        sMx = fmaxf(fmaxf(smx[0], smx[1]), fmaxf(smx[2], smx[3]));
    }
    __syncthreads();
    const float mnv = sMn;
    const float inv = 1.f / (epsp[0] + sMx - mnv);
    const int c = tid >> 5;                   // 0..7 (d-chunk)
    const int oi = tid & 31;                  // 0..31 (output slot)
    const int o = o0 + ((oi < 25) ? oi : 24); // clamped: always < 100
    const float* wmp = Wm + (size_t)(c * 32) * OUTD + o;
    const float* fr = frow + c * 32;
    float a0 = 0.f, a1 = 0.f, a2 = 0.f, a3 = 0.f;
    #pragma unroll
    for (int k2 = 0; k2 < 32; k2 += 4) {      // 4 independent chains (ILP)
        a0 = fmaf(fr[k2 + 0] - mnv, wmp[(k2 + 0) * OUTD], a0);
        a1 = fmaf(fr[k2 + 1] - mnv, wmp[(k2 + 1) * OUTD], a1);
        a2 = fmaf(fr[k2 + 2] - mnv, wmp[(k2 + 2) * OUTD], a2);
        a3 = fmaf(fr[k2 + 3] - mnv, wmp[(k2 + 3) * OUTD], a3);
    }
    spart[c][oi] = (a0 + a1) + (a2 + a3);
    __syncthreads();
    if (tid < 25) {
        float acc = 0.f;
        #pragma unroll
        for (int j = 0; j < 8; ++j) acc += spart[j][tid];
        out[g * OUTD + o0 + tid] = acc * inv + bm[o0 + tid];
    }
}

extern "C" void kernel_launch(void* const* d_in, const int* in_sizes, int n_in,
                              void* d_out, int out_size, void* d_ws, size_t ws_size,
                              hipStream_t stream) {
    const float* atomic_num = (const float*)d_in[0];
    const float* length     = (const float*)d_in[1];
    const int*   src        = (const int*)d_in[2];
    const int*   dst        = (const int*)d_in[3];
    const int*   gid        = (const int*)d_in[4];
    const float* W_node     = (const float*)d_in[5];
    const float* b_node     = (const float*)d_in[6];
    const float* W_edge     = (const float*)d_in[7];
    const float* b_edge     = (const float*)d_in[8];
    const float* gine_eps   = (const float*)d_in[9];
    const float* W_gnn      = (const float*)d_in[10];
    const float* b_gnn      = (const float*)d_in[11];
    const float* eps_param  = (const float*)d_in[12];
    const float* W_mlp      = (const float*)d_in[13];
    const float* b_mlp      = (const float*)d_in[14];
    float* out = (float*)d_out;

    // workspace (~29 MB). feat+cnt adjacent -> one memset zeroes both.
    float* feat = (float*)d_ws;                                   // G*D
    int* cnt    = (int*)(feat + (size_t)N_GRAPHS * DIM);          // N*2*CURPAD
    int2* epack = (int2*)(cnt + (size_t)N_NODES * 2 * CURPAD);    // N*CAP
    unsigned short* hbf0 = (unsigned short*)(epack + (size_t)N_NODES * CAP);
    unsigned short* hbf1 = hbf0 + (size_t)N_NODES * DIM;          // [N][256]
    unsigned short* xbf  = hbf1 + (size_t)N_NODES * DIM;          // [N][256]
    unsigned short* WgT  = xbf + (size_t)N_NODES * DIM;           // 2*256*256

    hipMemsetAsync(d_ws, 0,
                   (size_t)N_GRAPHS * DIM * 4 + (size_t)N_NODES * 2 * CURPAD * 4,
                   stream);
    // fused: fill || Wg transpose || node embedding (7 dispatches total)
    setup_k<<<2562, 256, 0, stream>>>(
        src, dst, length, cnt, epack, W_node, W_gnn, WgT,
        atomic_num, b_node, b_edge, hbf0);

    // GINE layer 0: hbf0 -> xbf -> hbf1
    gather_k<<<5000, 256, 0, stream>>>(
        hbf0, cnt, epack, W_edge, b_edge, gine_eps, 0, xbf);
    update_k<<<1280, 256, 0, stream>>>(
        xbf, WgT, b_gnn, b_edge, hbf1, gid, feat, 0);
    // GINE layer 1: hbf1 -> xbf -> feat (pooled)
    gather_k<<<5000, 256, 0, stream>>>(
        hbf1, cnt, epack, W_edge, b_edge, gine_eps, 1, xbf);
    update_k<<<1280, 256, 0, stream>>>(
        xbf, WgT + 256 * 256, b_gnn + DIM, b_edge, hbf0, gid, feat, 1);

    // fused minmax + normalize + head (parallel version)
    headmm_k<<<N_GRAPHS * 4, 256, 0, stream>>>(feat, W_mlp, b_mlp, eps_param, out);
}

// Round 15
// 181.852 us; speedup vs baseline: 1.0262x; 1.0262x over previous
//
#include <hip/hip_runtime.h>
#include <hip/hip_bf16.h>

#define N_NODES 10000
#define N_EDGES 320000
#define N_GRAPHS 64
#define DIM 256
#define ADIM 118
#define OUTD 100
#define CAP 96           // fixed CSR slots per node (mean degree 32, max ~66)
#define CURPAD 16        // ints per counter slot -> one 64B line per counter

typedef short bf8_t __attribute__((ext_vector_type(8)));
typedef float f4_t  __attribute__((ext_vector_type(4)));
typedef float f2_t  __attribute__((ext_vector_type(2)));

__device__ __forceinline__ unsigned short f2bf(float f) {
    unsigned u = __float_as_uint(f);
    u += 0x7FFFu + ((u >> 16) & 1u);   // round-to-nearest-even
    return (unsigned short)(u >> 16);
}
__device__ __forceinline__ float bf2f(unsigned short s) {
    return __uint_as_float(((unsigned)s) << 16);
}
__device__ __forceinline__ f2_t pk_fma(f2_t a, f2_t b, f2_t c) {
    f2_t d;
    asm("v_pk_fma_f32 %0, %1, %2, %3" : "=v"(d) : "v"(a), "v"(b), "v"(c));
    return d;
}
__device__ __forceinline__ f2_t pk_add(f2_t a, f2_t b) {
    f2_t d;
    asm("v_pk_add_f32 %0, %1, %2" : "=v"(d) : "v"(a), "v"(b));
    return d;
}

// ====== fused setup: CSR fill (0-1249) || Wg transpose (1250-1281) ||
// ====== node embedding (1282-2561, reads Wn directly — no WnT dependency)
#define AST 136
__global__ __launch_bounds__(256) void setup_k(
    const int* __restrict__ src, const int* __restrict__ dst,
    const float* __restrict__ len, int* __restrict__ cnt, int2* __restrict__ epack,
    const float* __restrict__ Wn, const float* __restrict__ Wg,
    unsigned short* __restrict__ WgT,
    const float* __restrict__ an, const float* __restrict__ bn,
    const float* __restrict__ be, unsigned short* __restrict__ hbf) {
    const int B = blockIdx.x;
    const int t = threadIdx.x;
    if (B < 1250) {
        // ---------- CSR fill: 1250*256 = 320000 edges exactly ----------
        int j = B * 256 + t;
        int d = dst[j];
        int pos = atomicAdd(&cnt[d << 4], 1);
        if (pos < CAP)
            epack[d * CAP + pos] = make_int2(src[j] * DIM, __float_as_int(len[j]));
        return;
    }
    if (B < 1282) {
        // ---------- Wg [2][256][256] f32 -> WgT bf16, LDS-tiled transpose ----------
        __shared__ unsigned short lds[64][65];    // +1 pad
        int r = B - 1250;
        int l = r >> 4; r &= 15;
        int kt = r & 3, ct = r >> 2;
        const float* srcp = Wg + l * 65536;
        unsigned short* dstp = WgT + l * 65536;
        #pragma unroll
        for (int i = 0; i < 16; ++i) {            // coalesced load 64x64 tile
            int idx = t + i * 256;
            int rr = idx >> 6, cc = idx & 63;
            lds[rr][cc] = f2bf(srcp[(size_t)(kt * 64 + rr) * 256 + ct * 64 + cc]);
        }
        __syncthreads();
        #pragma unroll
        for (int i = 0; i < 16; ++i) {            // coalesced transposed store
            int idx = t + i * 256;
            int r2 = idx >> 6, cc2 = idx & 63;
            dstp[(size_t)(ct * 64 + r2) * 256 + kt * 64 + cc2] = lds[cc2][r2];
        }
        return;
    }
    // ---------- node embedding: hbf = bf16(an @ W_node + b_node + b_edge) ----------
    // block = 16 rows x 128 cols (one dim-half); B-frags read Wn straight from
    // global (16-consecutive-col 64B segments, L2-resident) + in-reg f32->bf16.
    const int e = B - 1282;                       // 0..1279
    const int half = e & 1;
    const int tile = e >> 1;                      // 0..639
    if (tile >= 625) return;
    __shared__ __attribute__((aligned(16))) unsigned short xs[16 * AST];
    const int base = tile * 16;
    for (int i = t; i < 16 * (AST - ADIM); i += 256) {
        int r = i / (AST - ADIM);
        int c = i - r * (AST - ADIM);
        xs[r * AST + ADIM + c] = 0;
    }
    for (int i = t; i < 16 * 59; i += 256) {      // 118 = 2*59, float2 loads
        int r = i / 59;
        int c = (i - r * 59) * 2;
        float2 v = *(const float2*)(an + (size_t)(base + r) * ADIM + c);
        xs[r * AST + c]     = f2bf(v.x);
        xs[r * AST + c + 1] = f2bf(v.y);
    }
    __syncthreads();
    const int wave = t >> 6, lane = t & 63;
    const int m = lane & 15, quad = lane >> 4;
    bf8_t afrag[4];
    #pragma unroll
    for (int s = 0; s < 4; ++s)
        afrag[s] = *(const bf8_t*)&xs[m * AST + s * 32 + quad * 8];
    const int colbase = half * 128 + wave * 32;
    #pragma unroll
    for (int ct = 0; ct < 2; ++ct) {
        const int col = colbase + ct * 16 + m;
        f4_t acc = (f4_t){0.f, 0.f, 0.f, 0.f};
        #pragma unroll
        for (int s = 0; s < 4; ++s) {
            bf8_t bfrag;
            #pragma unroll
            for (int j = 0; j < 8; ++j) {
                int k = s * 32 + quad * 8 + j;
                float v = (k < ADIM) ? Wn[(size_t)k * DIM + col] : 0.f;
                bfrag[j] = (short)f2bf(v);
            }
            acc = __builtin_amdgcn_mfma_f32_16x16x32_bf16(afrag[s], bfrag, acc, 0, 0, 0);
        }
        float bb = bn[col] + be[col];             // fold b_edge
        #pragma unroll
        for (int r = 0; r < 4; ++r)
            hbf[(size_t)(base + quad * 4 + r) * DIM + col] = f2bf(acc[r] + bb);
    }
}

// ---------- gather: XCD-pinned dim-halves, packed-f32 inner math ----------
__global__ __launch_bounds__(256) void gather_k(
    const unsigned short* __restrict__ hbf, const int* __restrict__ cnt,
    const int2* __restrict__ epack, const float* __restrict__ We,
    const float* __restrict__ be, const float* __restrict__ epsp, int layer,
    unsigned short* __restrict__ xbf) {
    const int B = blockIdx.x;                 // grid = 5000
    const int half = (B >> 2) & 1;
    const int k = (B >> 3) * 4 + (B & 3);     // node tile [0, 2500)
    const int wave = threadIdx.x >> 6, lane = threadIdx.x & 63;
    const int node = __builtin_amdgcn_readfirstlane(k * 4 + wave);
    const int sub = lane >> 4;
    const int dp = half * 128 + (lane & 15) * 8;
    float4 wa = *(const float4*)(We + dp);
    float4 wc = *(const float4*)(We + dp + 4);
    f2_t ww[4];
    ww[0] = (f2_t){wa.x, wa.y}; ww[1] = (f2_t){wa.z, wa.w};
    ww[2] = (f2_t){wc.x, wc.y}; ww[3] = (f2_t){wc.z, wc.w};
    const float eps1 = 1.f + epsp[layer];
    float4 ba = *(const float4*)(be + dp);
    float4 bc = *(const float4*)(be + dp + 4);
    f2_t ebe[4];
    ebe[0] = (f2_t){eps1 * ba.x, eps1 * ba.y};
    ebe[1] = (f2_t){eps1 * ba.z, eps1 * ba.w};
    ebe[2] = (f2_t){eps1 * bc.x, eps1 * bc.y};
    ebe[3] = (f2_t){eps1 * bc.z, eps1 * bc.w};
    f2_t acc2[4];
    #pragma unroll
    for (int i = 0; i < 4; ++i) acc2[i] = (f2_t){0.f, 0.f};
    const unsigned short* hb = hbf + dp;
    const int ce = min(__builtin_amdgcn_readfirstlane(cnt[node << 4]), CAP);
    const int2* ep = epack + node * CAP;
#define GATH(q) { \
    const uint4 ar = *(const uint4*)(hb + (unsigned)(q).x); \
    const float l = __int_as_float((q).y); \
    f2_t lpk; lpk.x = l; lpk.y = l; \
    _Pragma("unroll") \
    for (int p = 0; p < 4; ++p) { \
        unsigned u = (&ar.x)[p]; \
        f2_t h; \
        h.x = __uint_as_float(u << 16); \
        h.y = __uint_as_float(u & 0xffff0000u); \
        f2_t mm = pk_fma(lpk, ww[p], h); \
        mm.x = fmaxf(mm.x, 0.f); \
        mm.y = fmaxf(mm.y, 0.f); \
        acc2[p] = pk_add(acc2[p], mm); \
    } }
    int t = 0;
    for (; t + 7 < ce; t += 8) {
        int2 qa = ep[t + sub], qb = ep[t + 4 + sub];
        GATH(qa) GATH(qb)
    }
    for (; t + 3 < ce; t += 4) {
        int2 q = ep[t + sub];
        GATH(q)
    }
    if (t < ce && t + sub < ce) {
        int2 q = ep[t + sub];
        GATH(q)
    }
#undef GATH
    #pragma unroll
    for (int p = 0; p < 4; ++p) {
        acc2[p].x += __shfl(acc2[p].x, lane ^ 16, 64);
        acc2[p].y += __shfl(acc2[p].y, lane ^ 16, 64);
        acc2[p].x += __shfl(acc2[p].x, lane ^ 32, 64);
        acc2[p].y += __shfl(acc2[p].y, lane ^ 32, 64);
    }
    if (sub == 0) {
        const uint4 hr = *(const uint4*)(hbf + (size_t)node * DIM + dp);
        bf8_t o;
        #pragma unroll
        for (int p = 0; p < 4; ++p) {
            unsigned u = (&hr.x)[p];
            float hlo = __uint_as_float(u << 16);
            float hhi = __uint_as_float(u & 0xffff0000u);
            o[2 * p]     = (short)f2bf(fmaf(eps1, hlo, acc2[p].x - ebe[p].x));
            o[2 * p + 1] = (short)f2bf(fmaf(eps1, hhi, acc2[p].y - ebe[p].y));
        }
        *(bf8_t*)(xbf + (size_t)node * DIM + dp) = o;
    }
}

// ---------- MFMA node update: block = 16 rows x 128 cols (one half) ----------
#define XST 264
__global__ __launch_bounds__(256) void update_k(
    const unsigned short* __restrict__ xbf,
    const unsigned short* __restrict__ WT, const float* __restrict__ b,
    const float* __restrict__ be, unsigned short* __restrict__ hout,
    const int* __restrict__ gid, float* __restrict__ feat, int do_pool) {
    const int B = blockIdx.x;                 // grid 1280, guard below
    const int half = (B >> 2) & 1;
    const int tile = (B >> 3) * 4 + (B & 3);
    if (tile >= 625) return;
    __shared__ __attribute__((aligned(16))) unsigned short xs[16 * XST];
    __shared__ int gids[16];
    const int base = tile * 16;
    const int tid = threadIdx.x;
    #pragma unroll
    for (int cch = tid; cch < 512; cch += 256) {     // 16 rows x full 256 dims
        int rr = cch >> 5, k0 = (cch & 31) * 8;
        *(bf8_t*)&xs[rr * XST + k0] = *(const bf8_t*)(xbf + (size_t)(base + rr) * DIM + k0);
    }
    if (do_pool && tid < 16) gids[tid] = gid[base + tid];
    __syncthreads();
    const int wave = tid >> 6, lane = tid & 63;
    const int m = lane & 15, quad = lane >> 4;
    bf8_t afrag[8];
    #pragma unroll
    for (int s = 0; s < 8; ++s)
        afrag[s] = *(const bf8_t*)&xs[m * XST + s * 32 + quad * 8];
    const int colbase = half * 128 + wave * 32;
    #pragma unroll
    for (int ct = 0; ct < 2; ++ct) {
        const int col = colbase + ct * 16 + m;
        f4_t acc2 = (f4_t){0.f, 0.f, 0.f, 0.f};
        const unsigned short* wp = WT + (size_t)col * DIM + quad * 8;
        #pragma unroll
        for (int s = 0; s < 8; ++s) {
            bf8_t bfrag = *(const bf8_t*)(wp + s * 32);
            acc2 = __builtin_amdgcn_mfma_f32_16x16x32_bf16(afrag[s], bfrag, acc2, 0, 0, 0);
        }
        if (!do_pool) {
            const float bb = b[col] + be[col];   // fold b_edge for next gather
            #pragma unroll
            for (int r = 0; r < 4; ++r)
                hout[(size_t)(base + quad * 4 + r) * DIM + col] = f2bf(acc2[r] + bb);
        } else {
            const float bb = b[col];
            if (gids[0] == gids[15]) {
                float v = acc2[0] + acc2[1] + acc2[2] + acc2[3] + 4.f * bb;
                v += __shfl(v, lane ^ 16, 64);
                v += __shfl(v, lane ^ 32, 64);
                if (quad == 0) atomicAdd(&feat[(size_t)gids[0] * DIM + col], v);
            } else {
                float run = 0.f;
                int cur = gids[quad * 4];
                #pragma unroll
                for (int r = 0; r < 4; ++r) {
                    int g = gids[quad * 4 + r];
                    if (g != cur) {
                        atomicAdd(&feat[(size_t)cur * DIM + col], run);
                        run = 0.f;
                        cur = g;
                    }
                    run += acc2[r] + bb;
                }
                atomicAdd(&feat[(size_t)cur * DIM + col], run);
            }
        }
    }
}

// ---------- parallel head: 256 blocks (4/graph, 25 outputs each) ----------
__global__ __launch_bounds__(256) void headmm_k(
    const float* __restrict__ feat, const float* __restrict__ Wm,
    const float* __restrict__ bm, const float* __restrict__ epsp,
    float* __restrict__ out) {
    __shared__ float frow[DIM];
    __shared__ float smn[4], smx[4], sMn, sMx;
    __shared__ float spart[8][32];
    const int g  = blockIdx.x >> 2;           // graph
    const int o0 = (blockIdx.x & 3) * 25;     // output base (o0+24 <= 99)
    const int tid = threadIdx.x;
    const int wave = tid >> 6, lane = tid & 63;
    float mn = 3.4e38f, mx = -3.4e38f;
    const float4* f4 = (const float4*)feat;
    for (int i = tid; i < N_GRAPHS * DIM / 4; i += 256) {   // 16 iterations
        float4 v = f4[i];
        mn = fminf(mn, fminf(fminf(v.x, v.y), fminf(v.z, v.w)));
        mx = fmaxf(mx, fmaxf(fmaxf(v.x, v.y), fmaxf(v.z, v.w)));
    }
    frow[tid] = feat[g * DIM + tid];
    #pragma unroll
    for (int off = 32; off > 0; off >>= 1) {
        mn = fminf(mn, __shfl_down(mn, off, 64));
        mx = fmaxf(mx, __shfl_down(mx, off, 64));
    }
    if (lane == 0) { smn[wave] = mn; smx[wave] = mx; }
    __syncthreads();
    if (tid == 0) {
        sMn = fminf(fminf(smn[0], smn[1]), fminf(smn[2], smn[3]));
        sMx = fmaxf(fmaxf(smx[0], smx[1]), fmaxf(smx[2], smx[3]));
    }
    __syncthreads();
    const float mnv = sMn;
    const float inv = 1.f / (epsp[0] + sMx - mnv);
    const int c = tid >> 5;                   // 0..7 (d-chunk)
    const int oi = tid & 31;                  // 0..31 (output slot)
    const int o = o0 + ((oi < 25) ? oi : 24); // clamped: always < 100
    const float* wmp = Wm + (size_t)(c * 32) * OUTD + o;
    const float* fr = frow + c * 32;
    float a0 = 0.f, a1 = 0.f, a2 = 0.f, a3 = 0.f;
    #pragma unroll
    for (int k2 = 0; k2 < 32; k2 += 4) {      // 4 independent chains (ILP)
        a0 = fmaf(fr[k2 + 0] - mnv, wmp[(k2 + 0) * OUTD], a0);
        a1 = fmaf(fr[k2 + 1] - mnv, wmp[(k2 + 1) * OUTD], a1);
        a2 = fmaf(fr[k2 + 2] - mnv, wmp[(k2 + 2) * OUTD], a2);
        a3 = fmaf(fr[k2 + 3] - mnv, wmp[(k2 + 3) * OUTD], a3);
    }
    spart[c][oi] = (a0 + a1) + (a2 + a3);
    __syncthreads();
    if (tid < 25) {
        float acc = 0.f;
        #pragma unroll
        for (int j = 0; j < 8; ++j) acc += spart[j][tid];
        out[g * OUTD + o0 + tid] = acc * inv + bm[o0 + tid];
    }
}

extern "C" void kernel_launch(void* const* d_in, const int* in_sizes, int n_in,
                              void* d_out, int out_size, void* d_ws, size_t ws_size,
                              hipStream_t stream) {
    const float* atomic_num = (const float*)d_in[0];
    const float* length     = (const float*)d_in[1];
    const int*   src        = (const int*)d_in[2];
    const int*   dst        = (const int*)d_in[3];
    const int*   gid        = (const int*)d_in[4];
    const float* W_node     = (const float*)d_in[5];
    const float* b_node     = (const float*)d_in[6];
    const float* W_edge     = (const float*)d_in[7];
    const float* b_edge     = (const float*)d_in[8];
    const float* gine_eps   = (const float*)d_in[9];
    const float* W_gnn      = (const float*)d_in[10];
    const float* b_gnn      = (const float*)d_in[11];
    const float* eps_param  = (const float*)d_in[12];
    const float* W_mlp      = (const float*)d_in[13];
    const float* b_mlp      = (const float*)d_in[14];
    float* out = (float*)d_out;

    // workspace (~24 MB). feat+cnt adjacent -> one memset zeroes both.
    float* feat = (float*)d_ws;                                   // G*D
    int* cnt    = (int*)(feat + (size_t)N_GRAPHS * DIM);          // N*CURPAD
    int2* epack = (int2*)(cnt + (size_t)N_NODES * CURPAD);        // N*CAP
    unsigned short* hbf0 = (unsigned short*)(epack + (size_t)N_NODES * CAP);
    unsigned short* hbf1 = hbf0 + (size_t)N_NODES * DIM;          // [N][256]
    unsigned short* xbf  = hbf1 + (size_t)N_NODES * DIM;          // [N][256]
    unsigned short* WgT  = xbf + (size_t)N_NODES * DIM;           // 2*256*256

    hipMemsetAsync(d_ws, 0,
                   (size_t)N_GRAPHS * DIM * 4 + (size_t)N_NODES * CURPAD * 4,
                   stream);
    // fused: fill || Wg transpose || node embedding (7 dispatches total)
    setup_k<<<2562, 256, 0, stream>>>(
        src, dst, length, cnt, epack, W_node, W_gnn, WgT,
        atomic_num, b_node, b_edge, hbf0);

    // GINE layer 0: hbf0 -> xbf -> hbf1
    gather_k<<<5000, 256, 0, stream>>>(
        hbf0, cnt, epack, W_edge, b_edge, gine_eps, 0, xbf);
    update_k<<<1280, 256, 0, stream>>>(
        xbf, WgT, b_gnn, b_edge, hbf1, gid, feat, 0);
    // GINE layer 1: hbf1 -> xbf -> feat (pooled)
    gather_k<<<5000, 256, 0, stream>>>(
        hbf1, cnt, epack, W_edge, b_edge, gine_eps, 1, xbf);
    update_k<<<1280, 256, 0, stream>>>(
        xbf, WgT + 256 * 256, b_gnn + DIM, b_edge, hbf0, gid, feat, 1);

    // fused minmax + normalize + head (parallel version)
    headmm_k<<<N_GRAPHS * 4, 256, 0, stream>>>(feat, W_mlp, b_mlp, eps_param, out);
}